// Round 1
// baseline (1295.378 us; speedup 1.0000x reference)
//
#include <hip/hip_runtime.h>
#include <math.h>

#define NN 10000
#define EE 160000
#define FI 32
#define DE 8
#define HD 64
#define TT 3
#define OD 12

// ---------------- CSR construction ----------------

__global__ __launch_bounds__(256) void hist_k(const int* __restrict__ ei, int* __restrict__ cnt) {
  int e = blockIdx.x * 256 + threadIdx.x;
  if (e < EE) atomicAdd(&cnt[ei[EE + e]], 1);
}

__global__ __launch_bounds__(1024) void scan_k(const int* __restrict__ cnt, int* __restrict__ rowptr) {
  __shared__ int buf[1024];
  __shared__ int carry_s;
  int tid = threadIdx.x;
  if (tid == 0) carry_s = 0;
  __syncthreads();
  for (int base = 0; base < NN; base += 1024) {
    int i = base + tid;
    int v = (i < NN) ? cnt[i] : 0;
    buf[tid] = v;
    __syncthreads();
    for (int off = 1; off < 1024; off <<= 1) {
      int add = (tid >= off) ? buf[tid - off] : 0;
      __syncthreads();
      buf[tid] += add;
      __syncthreads();
    }
    int incl = buf[tid];
    int carry = carry_s;
    if (i < NN) rowptr[i] = carry + incl - v;   // exclusive scan
    __syncthreads();
    if (tid == 1023) carry_s = carry + buf[1023];
    __syncthreads();
  }
  if (tid == 0) rowptr[NN] = carry_s;           // == EE
}

__global__ __launch_bounds__(256) void scatter_k(const int* __restrict__ ei, const int* __restrict__ rowptr,
                                                 int* __restrict__ cursor, int* __restrict__ col_src,
                                                 int* __restrict__ col_eid) {
  int e = blockIdx.x * 256 + threadIdx.x;
  if (e >= EE) return;
  int s = ei[e], d = ei[EE + e];
  int pos = rowptr[d] + atomicAdd(&cursor[d], 1);
  col_src[pos] = s;
  col_eid[pos] = e;
}

// mean of incoming edge_attr per dst (self-loop fill value)
__global__ __launch_bounds__(256) void meanea_k(const float* __restrict__ ea, const int* __restrict__ rowptr,
                                                const int* __restrict__ col_eid, float* __restrict__ mea) {
  int idx = blockIdx.x * 256 + threadIdx.x;
  if (idx >= NN * DE) return;
  int n = idx >> 3, dd = idx & 7;
  int r0 = rowptr[n], r1 = rowptr[n + 1];
  float s = 0.f;
  for (int p = r0; p < r1; ++p) s += ea[(size_t)col_eid[p] * DE + dd];
  int deg = r1 - r0;
  mea[idx] = s / (float)(deg > 0 ? deg : 1);
}

// ---------------- node phase: xl = inp @ Wl + bl for 8 convs ----------------
// grid (NN, 2): y = branch (0 = x-branch K=32, 1 = h-branch K=64); 4 waves = 4 gates.

__global__ __launch_bounds__(256) void node_k(const float* __restrict__ x_t, const float* __restrict__ h,
                                              const float* __restrict__ Wl_x, const float* __restrict__ bl_x,
                                              const float* __restrict__ Wl_h, const float* __restrict__ bl_h,
                                              float* __restrict__ xl) {
  int n = blockIdx.x;
  int b = blockIdx.y;
  int k = threadIdx.x >> 6;
  int lane = threadIdx.x & 63;
  __shared__ float inp[HD];
  int K = b ? HD : FI;
  const float* srcrow = b ? (h + (size_t)n * HD) : (x_t + (size_t)n * FI);
  if (threadIdx.x < K) inp[threadIdx.x] = srcrow[threadIdx.x];
  __syncthreads();
  const float* W = (b ? Wl_h : Wl_x) + (size_t)k * K * HD;
  float a = (b ? bl_h : bl_x)[k * HD + lane];
  for (int kk = 0; kk < K; ++kk) a += inp[kk] * W[kk * HD + lane];
  xl[(((size_t)b * 4 + k) * NN + n) * HD + lane] = a;
}

// ---------------- fused edge phase (8 GATv2 convs) + LSTM gate update + LayerNorm ----------------
// One 64-lane wave per dst node. lane j = channel j (head = j>>5).

__global__ __launch_bounds__(64) void edge_update_k(
    const float* __restrict__ x_t, const float* __restrict__ edge_attr,
    const int* __restrict__ rowptr, const int* __restrict__ col_src, const int* __restrict__ col_eid,
    const float* __restrict__ mea, const float* __restrict__ xl,
    const float* __restrict__ Wr_x, const float* __restrict__ br_x,
    const float* __restrict__ Wr_h, const float* __restrict__ br_h,
    const float* __restrict__ We_x, const float* __restrict__ We_h,
    const float* __restrict__ att_x, const float* __restrict__ att_h,
    const float* __restrict__ bias_x, const float* __restrict__ bias_h,
    const float* __restrict__ ln_w, const float* __restrict__ ln_b,
    float* __restrict__ h, float* __restrict__ c) {
  const int d = blockIdx.x;
  const int lane = threadIdx.x;

  __shared__ float xs[FI];
  __shared__ float hs[HD];
  __shared__ float ea_s[DE][64];   // transposed: write bank-friendly, read broadcast
  __shared__ int src_s[64];

  if (lane < FI) xs[lane] = x_t[(size_t)d * FI + lane];
  hs[lane] = h[(size_t)d * HD + lane];
  __syncthreads();

  float xr[8], attv[8], acc[8], den[8];
#pragma unroll
  for (int bk = 0; bk < 8; ++bk) {
    const int k = bk & 3;
    const bool isx = (bk < 4);
    const int K = isx ? FI : HD;
    const float* W = (isx ? Wr_x : Wr_h) + (size_t)k * K * HD;
    float a = (isx ? br_x : br_h)[k * HD + lane];
    for (int kk = 0; kk < K; ++kk) a += (isx ? xs[kk] : hs[kk]) * W[kk * HD + lane];
    xr[bk] = a;
    attv[bk] = (isx ? att_x : att_h)[k * HD + lane];
    acc[bk] = 0.f;
    den[bk] = 0.f;
  }

  const int r0 = rowptr[d];
  const int total = (rowptr[d + 1] - r0) + 1;  // + self loop

  for (int base = 0; base < total; base += 64) {
    const int m = min(64, total - base);
    __syncthreads();
    if (lane < m) {
      const int idx = base + lane;
      int s;
      const float* eap;
      if (idx < total - 1) {
        const int pp = r0 + idx;
        s = col_src[pp];
        eap = edge_attr + (size_t)col_eid[pp] * DE;
      } else {  // self loop, attr = mean of incoming
        s = d;
        eap = mea + (size_t)d * DE;
      }
      src_s[lane] = s;
#pragma unroll
      for (int dd = 0; dd < DE; ++dd) ea_s[dd][lane] = eap[dd];
    }
    __syncthreads();

#pragma unroll
    for (int bk = 0; bk < 8; ++bk) {
      const int k = bk & 3;
      const bool isx = (bk < 4);
      const float* Wep = (isx ? We_x : We_h) + (size_t)k * DE * HD;
      float we[DE];
#pragma unroll
      for (int dd = 0; dd < DE; ++dd) we[dd] = Wep[dd * HD + lane];
      const float* xlb = xl + (size_t)bk * NN * HD;
      const float xrv = xr[bk], av = attv[bk];
      float a_acc = acc[bk], a_den = den[bk];
      for (int e = 0; e < m; ++e) {
        const float xlv = xlb[(size_t)src_s[e] * HD + lane];
        float ev = 0.f;
#pragma unroll
        for (int dd = 0; dd < DE; ++dd) ev += ea_s[dd][e] * we[dd];
        float sv = xlv + xrv + ev;
        sv = (sv >= 0.f) ? sv : 0.2f * sv;            // leaky_relu(0.2)
        float tv = sv * av;                            // att dot, per head
#pragma unroll
        for (int o = 16; o >= 1; o >>= 1) tv += __shfl_xor(tv, o, 32);
        const float aexp = __expf(tv);                 // max-free softmax (safe range)
        a_acc += aexp * xlv;
        a_den += aexp;
      }
      acc[bk] = a_acc;
      den[bk] = a_den;
    }
  }

  // LSTM gates: i,f,o,g  (gx[k] + gh[k]), then c/h update + LayerNorm, all in-register
  float g4[4];
#pragma unroll
  for (int k = 0; k < 4; ++k)
    g4[k] = (acc[k] / den[k] + bias_x[k * HD + lane]) + (acc[4 + k] / den[4 + k] + bias_h[k * HD + lane]);

  const float iv = 1.f / (1.f + __expf(-g4[0]));
  const float fv = 1.f / (1.f + __expf(-g4[1]));
  const float ov = 1.f / (1.f + __expf(-g4[2]));
  const float gv = tanhf(g4[3]);
  const float cold = c[(size_t)d * HD + lane];
  const float cn = fv * cold + iv * gv;
  const float nt = ov * tanhf(cn);

  float mu = nt;
#pragma unroll
  for (int o = 32; o >= 1; o >>= 1) mu += __shfl_xor(mu, o, 64);
  mu *= (1.f / 64.f);
  const float df = nt - mu;
  float v2 = df * df;
#pragma unroll
  for (int o = 32; o >= 1; o >>= 1) v2 += __shfl_xor(v2, o, 64);
  v2 *= (1.f / 64.f);
  const float hn = df * rsqrtf(v2 + 1e-5f) * ln_w[lane] + ln_b[lane];

  c[(size_t)d * HD + lane] = cn;
  h[(size_t)d * HD + lane] = hn;
}

// ---------------- output MLP: gelu(h@w1+b1)@w2+b2 ----------------

__global__ __launch_bounds__(64) void out_k(const float* __restrict__ h,
                                            const float* __restrict__ w1, const float* __restrict__ b1,
                                            const float* __restrict__ w2, const float* __restrict__ b2,
                                            float* __restrict__ out) {
  const int n = blockIdx.x;
  const int j = threadIdx.x;
  __shared__ float hsm[HD];
  __shared__ float zs[HD];
  hsm[j] = h[(size_t)n * HD + j];
  __syncthreads();
  float a = b1[j];
  for (int kk = 0; kk < HD; ++kk) a += hsm[kk] * w1[kk * HD + j];
  const float z = 0.5f * a * (1.f + erff(a * 0.70710678118654752f));  // exact (erf) GELU
  zs[j] = z;
  __syncthreads();
  if (j < OD) {
    float o = b2[j];
    for (int kk = 0; kk < HD; ++kk) o += zs[kk] * w2[kk * OD + j];
    out[(size_t)n * OD + j] = o;
  }
}

// ---------------- host orchestration ----------------

extern "C" void kernel_launch(void* const* d_in, const int* in_sizes, int n_in,
                              void* d_out, int out_size, void* d_ws, size_t ws_size,
                              hipStream_t stream) {
  const float* x_seq   = (const float*)d_in[0];
  const float* edge_attr = (const float*)d_in[1];
  const int*   ei      = (const int*)d_in[2];
  const float* Wl_x    = (const float*)d_in[3];
  const float* bl_x    = (const float*)d_in[4];
  const float* Wr_x    = (const float*)d_in[5];
  const float* br_x    = (const float*)d_in[6];
  const float* We_x    = (const float*)d_in[7];
  const float* att_x   = (const float*)d_in[8];
  const float* bias_x  = (const float*)d_in[9];
  const float* Wl_h    = (const float*)d_in[10];
  const float* bl_h    = (const float*)d_in[11];
  const float* Wr_h    = (const float*)d_in[12];
  const float* br_h    = (const float*)d_in[13];
  const float* We_h    = (const float*)d_in[14];
  const float* att_h   = (const float*)d_in[15];
  const float* bias_h  = (const float*)d_in[16];
  const float* ln_w    = (const float*)d_in[17];
  const float* ln_b    = (const float*)d_in[18];
  const float* w1      = (const float*)d_in[19];
  const float* b1      = (const float*)d_in[20];
  const float* w2      = (const float*)d_in[21];
  const float* b2      = (const float*)d_in[22];
  float* out = (float*)d_out;

  char* p = (char*)d_ws;
  size_t off = 0;
  auto take = [&](size_t bytes) -> char* {
    char* r = p + off;
    off += (bytes + 255) & ~(size_t)255;
    return r;
  };
  int*   rowptr  = (int*)take((NN + 1) * sizeof(int));
  int*   cnt     = (int*)take(NN * sizeof(int));
  int*   cursor  = (int*)take(NN * sizeof(int));
  int*   col_src = (int*)take(EE * sizeof(int));
  int*   col_eid = (int*)take(EE * sizeof(int));
  float* mea     = (float*)take((size_t)NN * DE * sizeof(float));
  float* xl      = (float*)take((size_t)8 * NN * HD * sizeof(float));
  float* hbuf    = (float*)take((size_t)NN * HD * sizeof(float));
  float* cbuf    = (float*)take((size_t)NN * HD * sizeof(float));

  hipMemsetAsync(cnt, 0, NN * sizeof(int), stream);
  hipMemsetAsync(cursor, 0, NN * sizeof(int), stream);
  hipMemsetAsync(hbuf, 0, (size_t)NN * HD * sizeof(float), stream);
  hipMemsetAsync(cbuf, 0, (size_t)NN * HD * sizeof(float), stream);

  hist_k<<<(EE + 255) / 256, 256, 0, stream>>>(ei, cnt);
  scan_k<<<1, 1024, 0, stream>>>(cnt, rowptr);
  scatter_k<<<(EE + 255) / 256, 256, 0, stream>>>(ei, rowptr, cursor, col_src, col_eid);
  meanea_k<<<(NN * DE + 255) / 256, 256, 0, stream>>>(edge_attr, rowptr, col_eid, mea);

  for (int t = 0; t < TT; ++t) {
    const float* x_t = x_seq + (size_t)t * NN * FI;
    node_k<<<dim3(NN, 2), 256, 0, stream>>>(x_t, hbuf, Wl_x, bl_x, Wl_h, bl_h, xl);
    edge_update_k<<<NN, 64, 0, stream>>>(x_t, edge_attr, rowptr, col_src, col_eid, mea, xl,
                                         Wr_x, br_x, Wr_h, br_h, We_x, We_h, att_x, att_h,
                                         bias_x, bias_h, ln_w, ln_b, hbuf, cbuf);
  }
  out_k<<<NN, 64, 0, stream>>>(hbuf, w1, b1, w2, b2, out);
}

// Round 2
// 698.047 us; speedup vs baseline: 1.8557x; 1.8557x over previous
//
#include <hip/hip_runtime.h>
#include <math.h>

#define NN 10000
#define EE 160000
#define FI 32
#define DE 8
#define HD 64
#define TT 3
#define OD 12

// ---------------- CSR construction (padded: +1 self-loop slot per row) ----------------

__global__ __launch_bounds__(256) void hist_k(const int* __restrict__ ei, int* __restrict__ cnt) {
  int e = blockIdx.x * 256 + threadIdx.x;
  if (e < EE) atomicAdd(&cnt[ei[EE + e]], 1);
}

// rowptr2[i] = exclusive_scan(cnt)[i] + i  (each row padded by 1 for the self loop)
__global__ __launch_bounds__(1024) void scan_k(const int* __restrict__ cnt, int* __restrict__ rowptr2) {
  __shared__ int wsum[16];
  __shared__ int carry_s;
  int tid = threadIdx.x, lane = tid & 63, wid = tid >> 6;
  if (tid == 0) carry_s = 0;
  __syncthreads();
  for (int base = 0; base < NN; base += 1024) {
    int i = base + tid;
    int v = (i < NN) ? cnt[i] : 0;
    int s = v;
#pragma unroll
    for (int o = 1; o < 64; o <<= 1) {
      int t = __shfl_up(s, o, 64);
      if (lane >= o) s += t;
    }
    if (lane == 63) wsum[wid] = s;
    __syncthreads();
    if (wid == 0) {
      int ws = (lane < 16) ? wsum[lane] : 0;
#pragma unroll
      for (int o = 1; o < 16; o <<= 1) {
        int t = __shfl_up(ws, o, 64);
        if (lane >= o) ws += t;
      }
      if (lane < 16) wsum[lane] = ws;
    }
    __syncthreads();
    int woff = (wid > 0) ? wsum[wid - 1] : 0;
    int incl = s + woff;
    int carry = carry_s;
    if (i < NN) rowptr2[i] = carry + incl - v + i;
    __syncthreads();
    if (tid == 1023) carry_s = carry + incl;
    __syncthreads();
  }
  if (threadIdx.x == 0) rowptr2[NN] = carry_s + NN;
}

__global__ __launch_bounds__(256) void scatter_k(const int* __restrict__ ei, const int* __restrict__ rowptr2,
                                                 int* __restrict__ cursor, int* __restrict__ src_g,
                                                 int* __restrict__ pos_of_e) {
  int e = blockIdx.x * 256 + threadIdx.x;
  if (e >= EE) return;
  int s = ei[e], d = ei[EE + e];
  int pos = rowptr2[d] + atomicAdd(&cursor[d], 1);
  src_g[pos] = s;
  pos_of_e[e] = pos;
}

__global__ __launch_bounds__(256) void gather_ea_k(const float* __restrict__ ea, const int* __restrict__ pos_of_e,
                                                   float* __restrict__ ea_g) {
  int e = blockIdx.x * 256 + threadIdx.x;
  if (e >= EE) return;
  int pos = pos_of_e[e];
  const float4* s4 = reinterpret_cast<const float4*>(ea + (size_t)e * DE);
  float4* d4 = reinterpret_cast<float4*>(ea_g + (size_t)pos * DE);
  d4[0] = s4[0];
  d4[1] = s4[1];
}

// fill self-loop slot: attr = mean of incoming edge attrs, src = node itself
__global__ __launch_bounds__(256) void self_k(const int* __restrict__ rowptr2, int* __restrict__ src_g,
                                              float* __restrict__ ea_g) {
  int idx = blockIdx.x * 256 + threadIdx.x;
  if (idx >= NN * DE) return;
  int n = idx >> 3, dd = idx & 7;
  int r0 = rowptr2[n];
  int deg = rowptr2[n + 1] - r0 - 1;
  float s = 0.f;
  for (int j = 0; j < deg; ++j) s += ea_g[(size_t)(r0 + j) * DE + dd];
  ea_g[(size_t)(r0 + deg) * DE + dd] = s / (float)(deg > 0 ? deg : 1);
  if (dd == 0) src_g[r0 + deg] = n;
}

// ---------------- node phase: xl = inp@Wl+bl, xr = inp@Wr+br for 8 convs ----------------
// grid (NN, 2): y = branch (0: x, K=32; 1: h, K=64); 4 waves = 4 gates.

__global__ __launch_bounds__(256) void node_k(const float* __restrict__ x_t, const float* __restrict__ h,
                                              const float* __restrict__ Wl_x, const float* __restrict__ bl_x,
                                              const float* __restrict__ Wr_x, const float* __restrict__ br_x,
                                              const float* __restrict__ Wl_h, const float* __restrict__ bl_h,
                                              const float* __restrict__ Wr_h, const float* __restrict__ br_h,
                                              float* __restrict__ xl, float* __restrict__ xr) {
  int n = blockIdx.x, b = blockIdx.y;
  int k = threadIdx.x >> 6, lane = threadIdx.x & 63;
  __shared__ float inp[HD];
  int K = b ? HD : FI;
  const float* srcrow = b ? (h + (size_t)n * HD) : (x_t + (size_t)n * FI);
  if (threadIdx.x < K) inp[threadIdx.x] = srcrow[threadIdx.x];
  __syncthreads();
  const float* Wl = (b ? Wl_h : Wl_x) + (size_t)k * K * HD;
  const float* Wr = (b ? Wr_h : Wr_x) + (size_t)k * K * HD;
  float al = (b ? bl_h : bl_x)[k * HD + lane];
  float ar = (b ? br_h : br_x)[k * HD + lane];
  for (int kk = 0; kk < K; ++kk) {
    float v = inp[kk];
    al += v * Wl[kk * HD + lane];
    ar += v * Wr[kk * HD + lane];
  }
  size_t o = (((size_t)b * 4 + k) * NN + n) * HD + lane;
  xl[o] = al;
  xr[o] = ar;
}

// ---------------- edge phase: one wave per (node, conv) ----------------
// 4 independent waves per 256-thread block; no LDS, no barriers.

__global__ __launch_bounds__(256, 8) void edge_k(
    const int* __restrict__ rowptr2, const int* __restrict__ src_g, const float* __restrict__ ea_g,
    const float* __restrict__ xl, const float* __restrict__ xr,
    const float* __restrict__ att_x, const float* __restrict__ att_h,
    const float* __restrict__ We_x, const float* __restrict__ We_h,
    float* __restrict__ acc_b, float* __restrict__ den_b) {
  const int w = blockIdx.x * 4 + (threadIdx.x >> 6);
  const int lane = threadIdx.x & 63;
  const int d = w >> 3, bk = w & 7;
  if (d >= NN) return;
  const int k = bk & 3;
  const bool isx = (bk < 4);

  const float xrv = xr[((size_t)bk * NN + d) * HD + lane];
  const float attv = (isx ? att_x : att_h)[k * HD + lane];
  const float* Wep = (isx ? We_x : We_h) + (size_t)k * DE * HD;
  float we[DE];
#pragma unroll
  for (int dd = 0; dd < DE; ++dd) we[dd] = Wep[dd * HD + lane];
  const float* xlb = xl + (size_t)bk * NN * HD;
  const float4* eg4 = reinterpret_cast<const float4*>(ea_g);

  const int r0 = rowptr2[d];
  const int r1 = rowptr2[d + 1];
  float acc = 0.f, den = 0.f;

  int p = r0;
  for (; p + 4 <= r1; p += 4) {
    int s_[4];
    float xlv[4], tv[4];
#pragma unroll
    for (int i = 0; i < 4; ++i) s_[i] = src_g[p + i];
#pragma unroll
    for (int i = 0; i < 4; ++i) xlv[i] = xlb[(size_t)s_[i] * HD + lane];
#pragma unroll
    for (int i = 0; i < 4; ++i) {
      float4 ua = eg4[(size_t)(p + i) * 2];
      float4 ub = eg4[(size_t)(p + i) * 2 + 1];
      float ev = ua.x * we[0] + ua.y * we[1] + ua.z * we[2] + ua.w * we[3]
               + ub.x * we[4] + ub.y * we[5] + ub.z * we[6] + ub.w * we[7];
      float sv = xlv[i] + xrv + ev;
      sv = (sv >= 0.f) ? sv : 0.2f * sv;
      tv[i] = sv * attv;
    }
#pragma unroll
    for (int o = 16; o >= 1; o >>= 1) {
#pragma unroll
      for (int i = 0; i < 4; ++i) tv[i] += __shfl_xor(tv[i], o, 32);
    }
#pragma unroll
    for (int i = 0; i < 4; ++i) {
      float ax = __expf(tv[i]);
      acc += ax * xlv[i];
      den += ax;
    }
  }
  for (; p < r1; ++p) {
    int s = src_g[p];
    float xlv = xlb[(size_t)s * HD + lane];
    float4 ua = eg4[(size_t)p * 2];
    float4 ub = eg4[(size_t)p * 2 + 1];
    float ev = ua.x * we[0] + ua.y * we[1] + ua.z * we[2] + ua.w * we[3]
             + ub.x * we[4] + ub.y * we[5] + ub.z * we[6] + ub.w * we[7];
    float sv = xlv + xrv + ev;
    sv = (sv >= 0.f) ? sv : 0.2f * sv;
    float tv = sv * attv;
#pragma unroll
    for (int o = 16; o >= 1; o >>= 1) tv += __shfl_xor(tv, o, 32);
    float ax = __expf(tv);
    acc += ax * xlv;
    den += ax;
  }

  acc_b[((size_t)bk * NN + d) * HD + lane] = acc;
  if ((lane & 31) == 0) den_b[((size_t)bk * NN + d) * 2 + (lane >> 5)] = den;
}

// ---------------- combine: LSTM gates + LayerNorm; 4 nodes per block ----------------

__global__ __launch_bounds__(256, 8) void combine_k(
    const float* __restrict__ acc_b, const float* __restrict__ den_b,
    const float* __restrict__ bias_x, const float* __restrict__ bias_h,
    const float* __restrict__ ln_w, const float* __restrict__ ln_b,
    float* __restrict__ h, float* __restrict__ c) {
  int n = blockIdx.x * 4 + (threadIdx.x >> 6);
  int lane = threadIdx.x & 63;
  if (n >= NN) return;
  int head = lane >> 5;
  float g4[4];
#pragma unroll
  for (int k = 0; k < 4; ++k) {
    float ax = acc_b[((size_t)k * NN + n) * HD + lane];
    float dx = den_b[((size_t)k * NN + n) * 2 + head];
    float ah = acc_b[((size_t)(k + 4) * NN + n) * HD + lane];
    float dh = den_b[((size_t)(k + 4) * NN + n) * 2 + head];
    g4[k] = ax / dx + bias_x[k * HD + lane] + ah / dh + bias_h[k * HD + lane];
  }
  float iv = 1.f / (1.f + __expf(-g4[0]));
  float fv = 1.f / (1.f + __expf(-g4[1]));
  float ov = 1.f / (1.f + __expf(-g4[2]));
  float gv = tanhf(g4[3]);
  float cold = c[(size_t)n * HD + lane];
  float cn = fv * cold + iv * gv;
  float nt = ov * tanhf(cn);
  float mu = nt;
#pragma unroll
  for (int o = 32; o >= 1; o >>= 1) mu += __shfl_xor(mu, o, 64);
  mu *= (1.f / 64.f);
  float df = nt - mu;
  float v2 = df * df;
#pragma unroll
  for (int o = 32; o >= 1; o >>= 1) v2 += __shfl_xor(v2, o, 64);
  v2 *= (1.f / 64.f);
  float hn = df * rsqrtf(v2 + 1e-5f) * ln_w[lane] + ln_b[lane];
  c[(size_t)n * HD + lane] = cn;
  h[(size_t)n * HD + lane] = hn;
}

// ---------------- output MLP: gelu(h@w1+b1)@w2+b2; 4 nodes per block ----------------

__global__ __launch_bounds__(256) void out_k(const float* __restrict__ h,
                                             const float* __restrict__ w1, const float* __restrict__ b1,
                                             const float* __restrict__ w2, const float* __restrict__ b2,
                                             float* __restrict__ out) {
  int wv = threadIdx.x >> 6, j = threadIdx.x & 63;
  int n = blockIdx.x * 4 + wv;
  __shared__ float hsm[4][HD];
  __shared__ float zs[4][HD];
  if (n < NN) hsm[wv][j] = h[(size_t)n * HD + j];
  __syncthreads();
  float a = b1[j];
  for (int kk = 0; kk < HD; ++kk) a += hsm[wv][kk] * w1[kk * HD + j];
  zs[wv][j] = 0.5f * a * (1.f + erff(a * 0.70710678118654752f));
  __syncthreads();
  if (n < NN && j < OD) {
    float o = b2[j];
    for (int kk = 0; kk < HD; ++kk) o += zs[wv][kk] * w2[kk * OD + j];
    out[(size_t)n * OD + j] = o;
  }
}

// ---------------- host orchestration ----------------

extern "C" void kernel_launch(void* const* d_in, const int* in_sizes, int n_in,
                              void* d_out, int out_size, void* d_ws, size_t ws_size,
                              hipStream_t stream) {
  const float* x_seq   = (const float*)d_in[0];
  const float* edge_attr = (const float*)d_in[1];
  const int*   ei      = (const int*)d_in[2];
  const float* Wl_x    = (const float*)d_in[3];
  const float* bl_x    = (const float*)d_in[4];
  const float* Wr_x    = (const float*)d_in[5];
  const float* br_x    = (const float*)d_in[6];
  const float* We_x    = (const float*)d_in[7];
  const float* att_x   = (const float*)d_in[8];
  const float* bias_x  = (const float*)d_in[9];
  const float* Wl_h    = (const float*)d_in[10];
  const float* bl_h    = (const float*)d_in[11];
  const float* Wr_h    = (const float*)d_in[12];
  const float* br_h    = (const float*)d_in[13];
  const float* We_h    = (const float*)d_in[14];
  const float* att_h   = (const float*)d_in[15];
  const float* bias_h  = (const float*)d_in[16];
  const float* ln_w    = (const float*)d_in[17];
  const float* ln_b    = (const float*)d_in[18];
  const float* w1      = (const float*)d_in[19];
  const float* b1      = (const float*)d_in[20];
  const float* w2      = (const float*)d_in[21];
  const float* b2      = (const float*)d_in[22];
  float* out = (float*)d_out;

  char* p = (char*)d_ws;
  size_t off = 0;
  auto take = [&](size_t bytes) -> char* {
    char* r = p + off;
    off += (bytes + 255) & ~(size_t)255;
    return r;
  };
  int*   rowptr2  = (int*)take((NN + 1) * sizeof(int));
  int*   cnt      = (int*)take(NN * sizeof(int));
  int*   cursor   = (int*)take(NN * sizeof(int));
  int*   src_g    = (int*)take((EE + NN) * sizeof(int));
  int*   pos_of_e = (int*)take(EE * sizeof(int));
  float* ea_g     = (float*)take((size_t)(EE + NN) * DE * sizeof(float));
  float* xl       = (float*)take((size_t)8 * NN * HD * sizeof(float));
  float* xr       = (float*)take((size_t)8 * NN * HD * sizeof(float));
  float* acc_b    = (float*)take((size_t)8 * NN * HD * sizeof(float));
  float* den_b    = (float*)take((size_t)8 * NN * 2 * sizeof(float));
  float* hbuf     = (float*)take((size_t)NN * HD * sizeof(float));
  float* cbuf     = (float*)take((size_t)NN * HD * sizeof(float));

  hipMemsetAsync(cnt, 0, NN * sizeof(int), stream);
  hipMemsetAsync(cursor, 0, NN * sizeof(int), stream);
  hipMemsetAsync(hbuf, 0, (size_t)NN * HD * sizeof(float), stream);
  hipMemsetAsync(cbuf, 0, (size_t)NN * HD * sizeof(float), stream);

  hist_k<<<(EE + 255) / 256, 256, 0, stream>>>(ei, cnt);
  scan_k<<<1, 1024, 0, stream>>>(cnt, rowptr2);
  scatter_k<<<(EE + 255) / 256, 256, 0, stream>>>(ei, rowptr2, cursor, src_g, pos_of_e);
  gather_ea_k<<<(EE + 255) / 256, 256, 0, stream>>>(edge_attr, pos_of_e, ea_g);
  self_k<<<(NN * DE + 255) / 256, 256, 0, stream>>>(rowptr2, src_g, ea_g);

  for (int t = 0; t < TT; ++t) {
    const float* x_t = x_seq + (size_t)t * NN * FI;
    node_k<<<dim3(NN, 2), 256, 0, stream>>>(x_t, hbuf, Wl_x, bl_x, Wr_x, br_x,
                                            Wl_h, bl_h, Wr_h, br_h, xl, xr);
    edge_k<<<NN * 8 / 4, 256, 0, stream>>>(rowptr2, src_g, ea_g, xl, xr,
                                           att_x, att_h, We_x, We_h, acc_b, den_b);
    combine_k<<<(NN + 3) / 4, 256, 0, stream>>>(acc_b, den_b, bias_x, bias_h,
                                                ln_w, ln_b, hbuf, cbuf);
  }
  out_k<<<(NN + 3) / 4, 256, 0, stream>>>(hbuf, w1, b1, w2, b2, out);
}

// Round 3
// 359.506 us; speedup vs baseline: 3.6032x; 1.9417x over previous
//
#include <hip/hip_runtime.h>
#include <math.h>

#define NN 10000
#define EE 160000
#define FI 32
#define DE 8
#define HD 64
#define TT 3
#define OD 12

// ---------------- CSR construction (padded: +1 self-loop slot per row) ----------------

__global__ __launch_bounds__(256) void hist_k(const int* __restrict__ ei, int* __restrict__ cnt) {
  int e = blockIdx.x * 256 + threadIdx.x;
  if (e < EE) atomicAdd(&cnt[ei[EE + e]], 1);
}

// rowptr2[i] = exclusive_scan(cnt)[i] + i  (each row padded by 1 for the self loop)
__global__ __launch_bounds__(1024) void scan_k(const int* __restrict__ cnt, int* __restrict__ rowptr2) {
  __shared__ int wsum[16];
  __shared__ int carry_s;
  int tid = threadIdx.x, lane = tid & 63, wid = tid >> 6;
  if (tid == 0) carry_s = 0;
  __syncthreads();
  for (int base = 0; base < NN; base += 1024) {
    int i = base + tid;
    int v = (i < NN) ? cnt[i] : 0;
    int s = v;
#pragma unroll
    for (int o = 1; o < 64; o <<= 1) {
      int t = __shfl_up(s, o, 64);
      if (lane >= o) s += t;
    }
    if (lane == 63) wsum[wid] = s;
    __syncthreads();
    if (wid == 0) {
      int ws = (lane < 16) ? wsum[lane] : 0;
#pragma unroll
      for (int o = 1; o < 16; o <<= 1) {
        int t = __shfl_up(ws, o, 64);
        if (lane >= o) ws += t;
      }
      if (lane < 16) wsum[lane] = ws;
    }
    __syncthreads();
    int woff = (wid > 0) ? wsum[wid - 1] : 0;
    int incl = s + woff;
    int carry = carry_s;
    if (i < NN) rowptr2[i] = carry + incl - v + i;
    __syncthreads();
    if (tid == 1023) carry_s = carry + incl;
    __syncthreads();
  }
  if (threadIdx.x == 0) rowptr2[NN] = carry_s + NN;
}

__global__ __launch_bounds__(256) void scatter_k(const int* __restrict__ ei, const int* __restrict__ rowptr2,
                                                 int* __restrict__ cursor, int* __restrict__ src_g,
                                                 int* __restrict__ pos_of_e) {
  int e = blockIdx.x * 256 + threadIdx.x;
  if (e >= EE) return;
  int s = ei[e], d = ei[EE + e];
  int pos = rowptr2[d] + atomicAdd(&cursor[d], 1);
  src_g[pos] = s;
  pos_of_e[e] = pos;
}

__global__ __launch_bounds__(256) void gather_ea_k(const float* __restrict__ ea, const int* __restrict__ pos_of_e,
                                                   float* __restrict__ ea_g) {
  int e = blockIdx.x * 256 + threadIdx.x;
  if (e >= EE) return;
  int pos = pos_of_e[e];
  const float4* s4 = reinterpret_cast<const float4*>(ea + (size_t)e * DE);
  float4* d4 = reinterpret_cast<float4*>(ea_g + (size_t)pos * DE);
  d4[0] = s4[0];
  d4[1] = s4[1];
}

// fill self-loop slot: attr = mean of incoming edge attrs, src = node itself
__global__ __launch_bounds__(256) void self_k(const int* __restrict__ rowptr2, int* __restrict__ src_g,
                                              float* __restrict__ ea_g) {
  int idx = blockIdx.x * 256 + threadIdx.x;
  if (idx >= NN * DE) return;
  int n = idx >> 3, dd = idx & 7;
  int r0 = rowptr2[n];
  int deg = rowptr2[n + 1] - r0 - 1;
  float s = 0.f;
  for (int j = 0; j < deg; ++j) s += ea_g[(size_t)(r0 + j) * DE + dd];
  ea_g[(size_t)(r0 + deg) * DE + dd] = s / (float)(deg > 0 ? deg : 1);
  if (dd == 0) src_g[r0 + deg] = n;
}

// ---------------- node phase: xl/xr for 8 convs; 8 nodes per block (weight reuse) ----------------
// grid (NN/8, 2): y = branch (0: x, K=32; 1: h, K=64); 4 waves = 4 gates.

__global__ __launch_bounds__(256) void node_k(const float* __restrict__ x_t, const float* __restrict__ h,
                                              const float* __restrict__ Wl_x, const float* __restrict__ bl_x,
                                              const float* __restrict__ Wr_x, const float* __restrict__ br_x,
                                              const float* __restrict__ Wl_h, const float* __restrict__ bl_h,
                                              const float* __restrict__ Wr_h, const float* __restrict__ br_h,
                                              float* __restrict__ xl, float* __restrict__ xr) {
  const int n0 = blockIdx.x * 8;
  const int b = blockIdx.y;
  const int k = threadIdx.x >> 6;
  const int lane = threadIdx.x & 63;
  const int K = b ? HD : FI;
  __shared__ float inpT[HD][8];   // inpT[kk][j] = input feature kk of node n0+j
  const float* srcbase = b ? (h + (size_t)n0 * HD) : (x_t + (size_t)n0 * FI);
  for (int r = k; r < 8; r += 4)
    if (lane < K) inpT[lane][r] = srcbase[(size_t)r * K + lane];
  __syncthreads();

  const float* Wl = (b ? Wl_h : Wl_x) + (size_t)k * K * HD;
  const float* Wr = (b ? Wr_h : Wr_x) + (size_t)k * K * HD;
  const float blv = (b ? bl_h : bl_x)[k * HD + lane];
  const float brv = (b ? br_h : br_x)[k * HD + lane];
  float al[8], ar[8];
#pragma unroll
  for (int j = 0; j < 8; ++j) { al[j] = blv; ar[j] = brv; }
  for (int kk = 0; kk < K; ++kk) {
    const float wl = Wl[kk * HD + lane];
    const float wr = Wr[kk * HD + lane];
#pragma unroll
    for (int j = 0; j < 8; ++j) {
      const float v = inpT[kk][j];
      al[j] = fmaf(v, wl, al[j]);
      ar[j] = fmaf(v, wr, ar[j]);
    }
  }
#pragma unroll
  for (int j = 0; j < 8; ++j) {
    size_t o = (((size_t)b * 4 + k) * NN + (n0 + j)) * HD + lane;
    xl[o] = al[j];
    xr[o] = ar[j];
  }
}

// ---------------- edge phase: one wave per (conv, node); conv-major + XCD swizzle ----------------

#define SWZADD(t, imm) t += __int_as_float(__builtin_amdgcn_ds_swizzle(__float_as_int(t), imm))
#define REDUCE32(t) do { SWZADD(t, 0x041F); SWZADD(t, 0x081F); SWZADD(t, 0x101F); \
                         SWZADD(t, 0x201F); SWZADD(t, 0x401F); } while (0)

__global__ __launch_bounds__(256, 8) void edge_k(
    const int* __restrict__ rowptr2, const int* __restrict__ src_g, const float* __restrict__ ea_g,
    const float* __restrict__ xl, const float* __restrict__ xr,
    const float* __restrict__ att_x, const float* __restrict__ att_h,
    const float* __restrict__ We_x, const float* __restrict__ We_h,
    float* __restrict__ acc_b, float* __restrict__ den_b) {
  const int lane = threadIdx.x & 63;
  const int wid = threadIdx.x >> 6;
  // bijective XCD swizzle over 20000 blocks (20000 % 8 == 0): each XCD owns one conv bk
  const int bid = blockIdx.x;
  const int w = __builtin_amdgcn_readfirstlane(((bid & 7) * 2500 + (bid >> 3)) * 4 + wid);
  const int bk = w / NN;          // conv index 0..7 (scalar)
  const int d = w - bk * NN;      // dst node (scalar)
  const int k = bk & 3;
  const bool isx = (bk < 4);

  const float xrv = xr[((size_t)bk * NN + d) * HD + lane];
  const float attv = (isx ? att_x : att_h)[k * HD + lane];
  const float* Wep = (isx ? We_x : We_h) + (size_t)k * DE * HD;
  float we[DE];
#pragma unroll
  for (int dd = 0; dd < DE; ++dd) we[dd] = Wep[dd * HD + lane];
  const float* xlb = xl + (size_t)bk * NN * HD;
  const float4* eg4 = reinterpret_cast<const float4*>(ea_g);

  const int r0 = rowptr2[d];
  const int r1 = rowptr2[d + 1];
  float acc = 0.f, den = 0.f;

  int p = r0;
  for (; p + 4 <= r1; p += 4) {
    const int s0 = src_g[p + 0], s1 = src_g[p + 1], s2 = src_g[p + 2], s3 = src_g[p + 3];
    const float x0 = xlb[(size_t)s0 * HD + lane];
    const float x1 = xlb[(size_t)s1 * HD + lane];
    const float x2 = xlb[(size_t)s2 * HD + lane];
    const float x3 = xlb[(size_t)s3 * HD + lane];
    const float4 a0 = eg4[2 * (p + 0)], b0 = eg4[2 * (p + 0) + 1];
    const float4 a1 = eg4[2 * (p + 1)], b1 = eg4[2 * (p + 1) + 1];
    const float4 a2 = eg4[2 * (p + 2)], b2 = eg4[2 * (p + 2) + 1];
    const float4 a3 = eg4[2 * (p + 3)], b3 = eg4[2 * (p + 3) + 1];
    float t0 = x0 + xrv, t1 = x1 + xrv, t2 = x2 + xrv, t3 = x3 + xrv;
    t0 = fmaf(a0.x, we[0], t0); t1 = fmaf(a1.x, we[0], t1); t2 = fmaf(a2.x, we[0], t2); t3 = fmaf(a3.x, we[0], t3);
    t0 = fmaf(a0.y, we[1], t0); t1 = fmaf(a1.y, we[1], t1); t2 = fmaf(a2.y, we[1], t2); t3 = fmaf(a3.y, we[1], t3);
    t0 = fmaf(a0.z, we[2], t0); t1 = fmaf(a1.z, we[2], t1); t2 = fmaf(a2.z, we[2], t2); t3 = fmaf(a3.z, we[2], t3);
    t0 = fmaf(a0.w, we[3], t0); t1 = fmaf(a1.w, we[3], t1); t2 = fmaf(a2.w, we[3], t2); t3 = fmaf(a3.w, we[3], t3);
    t0 = fmaf(b0.x, we[4], t0); t1 = fmaf(b1.x, we[4], t1); t2 = fmaf(b2.x, we[4], t2); t3 = fmaf(b3.x, we[4], t3);
    t0 = fmaf(b0.y, we[5], t0); t1 = fmaf(b1.y, we[5], t1); t2 = fmaf(b2.y, we[5], t2); t3 = fmaf(b3.y, we[5], t3);
    t0 = fmaf(b0.z, we[6], t0); t1 = fmaf(b1.z, we[6], t1); t2 = fmaf(b2.z, we[6], t2); t3 = fmaf(b3.z, we[6], t3);
    t0 = fmaf(b0.w, we[7], t0); t1 = fmaf(b1.w, we[7], t1); t2 = fmaf(b2.w, we[7], t2); t3 = fmaf(b3.w, we[7], t3);
    t0 = fmaxf(t0, 0.2f * t0) * attv;
    t1 = fmaxf(t1, 0.2f * t1) * attv;
    t2 = fmaxf(t2, 0.2f * t2) * attv;
    t3 = fmaxf(t3, 0.2f * t3) * attv;
    REDUCE32(t0); REDUCE32(t1); REDUCE32(t2); REDUCE32(t3);
    const float e0 = __expf(t0), e1 = __expf(t1), e2 = __expf(t2), e3 = __expf(t3);
    acc = fmaf(e0, x0, acc); den += e0;
    acc = fmaf(e1, x1, acc); den += e1;
    acc = fmaf(e2, x2, acc); den += e2;
    acc = fmaf(e3, x3, acc); den += e3;
  }
  for (; p < r1; ++p) {
    const int s = src_g[p];
    const float xv = xlb[(size_t)s * HD + lane];
    const float4 a = eg4[2 * p], b = eg4[2 * p + 1];
    float t = xv + xrv;
    t = fmaf(a.x, we[0], t); t = fmaf(a.y, we[1], t); t = fmaf(a.z, we[2], t); t = fmaf(a.w, we[3], t);
    t = fmaf(b.x, we[4], t); t = fmaf(b.y, we[5], t); t = fmaf(b.z, we[6], t); t = fmaf(b.w, we[7], t);
    t = fmaxf(t, 0.2f * t) * attv;
    REDUCE32(t);
    const float ex = __expf(t);
    acc = fmaf(ex, xv, acc);
    den += ex;
  }

  acc_b[((size_t)bk * NN + d) * HD + lane] = acc;
  if ((lane & 31) == 0) den_b[((size_t)bk * NN + d) * 2 + (lane >> 5)] = den;
}

// ---------------- combine: LSTM gates + LayerNorm; 4 nodes per block ----------------

__global__ __launch_bounds__(256, 8) void combine_k(
    const float* __restrict__ acc_b, const float* __restrict__ den_b,
    const float* __restrict__ bias_x, const float* __restrict__ bias_h,
    const float* __restrict__ ln_w, const float* __restrict__ ln_b,
    float* __restrict__ h, float* __restrict__ c) {
  int n = blockIdx.x * 4 + (threadIdx.x >> 6);
  int lane = threadIdx.x & 63;
  if (n >= NN) return;
  int head = lane >> 5;
  float g4[4];
#pragma unroll
  for (int k = 0; k < 4; ++k) {
    float ax = acc_b[((size_t)k * NN + n) * HD + lane];
    float dx = den_b[((size_t)k * NN + n) * 2 + head];
    float ah = acc_b[((size_t)(k + 4) * NN + n) * HD + lane];
    float dh = den_b[((size_t)(k + 4) * NN + n) * 2 + head];
    g4[k] = ax / dx + bias_x[k * HD + lane] + ah / dh + bias_h[k * HD + lane];
  }
  float iv = 1.f / (1.f + __expf(-g4[0]));
  float fv = 1.f / (1.f + __expf(-g4[1]));
  float ov = 1.f / (1.f + __expf(-g4[2]));
  float gv = tanhf(g4[3]);
  float cold = c[(size_t)n * HD + lane];
  float cn = fv * cold + iv * gv;
  float nt = ov * tanhf(cn);
  float mu = nt;
#pragma unroll
  for (int o = 32; o >= 1; o >>= 1) mu += __shfl_xor(mu, o, 64);
  mu *= (1.f / 64.f);
  float df = nt - mu;
  float v2 = df * df;
#pragma unroll
  for (int o = 32; o >= 1; o >>= 1) v2 += __shfl_xor(v2, o, 64);
  v2 *= (1.f / 64.f);
  float hn = df * rsqrtf(v2 + 1e-5f) * ln_w[lane] + ln_b[lane];
  c[(size_t)n * HD + lane] = cn;
  h[(size_t)n * HD + lane] = hn;
}

// ---------------- output MLP: gelu(h@w1+b1)@w2+b2; 4 nodes per block ----------------

__global__ __launch_bounds__(256) void out_k(const float* __restrict__ h,
                                             const float* __restrict__ w1, const float* __restrict__ b1,
                                             const float* __restrict__ w2, const float* __restrict__ b2,
                                             float* __restrict__ out) {
  int wv = threadIdx.x >> 6, j = threadIdx.x & 63;
  int n = blockIdx.x * 4 + wv;
  __shared__ float hsm[4][HD];
  __shared__ float zs[4][HD];
  if (n < NN) hsm[wv][j] = h[(size_t)n * HD + j];
  __syncthreads();
  float a = b1[j];
  for (int kk = 0; kk < HD; ++kk) a += hsm[wv][kk] * w1[kk * HD + j];
  zs[wv][j] = 0.5f * a * (1.f + erff(a * 0.70710678118654752f));
  __syncthreads();
  if (n < NN && j < OD) {
    float o = b2[j];
    for (int kk = 0; kk < HD; ++kk) o += zs[wv][kk] * w2[kk * OD + j];
    out[(size_t)n * OD + j] = o;
  }
}

// ---------------- host orchestration ----------------

extern "C" void kernel_launch(void* const* d_in, const int* in_sizes, int n_in,
                              void* d_out, int out_size, void* d_ws, size_t ws_size,
                              hipStream_t stream) {
  const float* x_seq   = (const float*)d_in[0];
  const float* edge_attr = (const float*)d_in[1];
  const int*   ei      = (const int*)d_in[2];
  const float* Wl_x    = (const float*)d_in[3];
  const float* bl_x    = (const float*)d_in[4];
  const float* Wr_x    = (const float*)d_in[5];
  const float* br_x    = (const float*)d_in[6];
  const float* We_x    = (const float*)d_in[7];
  const float* att_x   = (const float*)d_in[8];
  const float* bias_x  = (const float*)d_in[9];
  const float* Wl_h    = (const float*)d_in[10];
  const float* bl_h    = (const float*)d_in[11];
  const float* Wr_h    = (const float*)d_in[12];
  const float* br_h    = (const float*)d_in[13];
  const float* We_h    = (const float*)d_in[14];
  const float* att_h   = (const float*)d_in[15];
  const float* bias_h  = (const float*)d_in[16];
  const float* ln_w    = (const float*)d_in[17];
  const float* ln_b    = (const float*)d_in[18];
  const float* w1      = (const float*)d_in[19];
  const float* b1      = (const float*)d_in[20];
  const float* w2      = (const float*)d_in[21];
  const float* b2      = (const float*)d_in[22];
  float* out = (float*)d_out;

  char* p = (char*)d_ws;
  size_t off = 0;
  auto take = [&](size_t bytes) -> char* {
    char* r = p + off;
    off += (bytes + 255) & ~(size_t)255;
    return r;
  };
  int*   rowptr2  = (int*)take((NN + 1) * sizeof(int));
  int*   cnt      = (int*)take(NN * sizeof(int));
  int*   cursor   = (int*)take(NN * sizeof(int));
  int*   src_g    = (int*)take((EE + NN) * sizeof(int));
  int*   pos_of_e = (int*)take(EE * sizeof(int));
  float* ea_g     = (float*)take((size_t)(EE + NN) * DE * sizeof(float));
  float* xl       = (float*)take((size_t)8 * NN * HD * sizeof(float));
  float* xr       = (float*)take((size_t)8 * NN * HD * sizeof(float));
  float* acc_b    = (float*)take((size_t)8 * NN * HD * sizeof(float));
  float* den_b    = (float*)take((size_t)8 * NN * 2 * sizeof(float));
  float* hbuf     = (float*)take((size_t)NN * HD * sizeof(float));
  float* cbuf     = (float*)take((size_t)NN * HD * sizeof(float));

  hipMemsetAsync(cnt, 0, NN * sizeof(int), stream);
  hipMemsetAsync(cursor, 0, NN * sizeof(int), stream);
  hipMemsetAsync(hbuf, 0, (size_t)NN * HD * sizeof(float), stream);
  hipMemsetAsync(cbuf, 0, (size_t)NN * HD * sizeof(float), stream);

  hist_k<<<(EE + 255) / 256, 256, 0, stream>>>(ei, cnt);
  scan_k<<<1, 1024, 0, stream>>>(cnt, rowptr2);
  scatter_k<<<(EE + 255) / 256, 256, 0, stream>>>(ei, rowptr2, cursor, src_g, pos_of_e);
  gather_ea_k<<<(EE + 255) / 256, 256, 0, stream>>>(edge_attr, pos_of_e, ea_g);
  self_k<<<(NN * DE + 255) / 256, 256, 0, stream>>>(rowptr2, src_g, ea_g);

  for (int t = 0; t < TT; ++t) {
    const float* x_t = x_seq + (size_t)t * NN * FI;
    node_k<<<dim3(NN / 8, 2), 256, 0, stream>>>(x_t, hbuf, Wl_x, bl_x, Wr_x, br_x,
                                                Wl_h, bl_h, Wr_h, br_h, xl, xr);
    edge_k<<<NN * 8 / 4, 256, 0, stream>>>(rowptr2, src_g, ea_g, xl, xr,
                                           att_x, att_h, We_x, We_h, acc_b, den_b);
    combine_k<<<(NN + 3) / 4, 256, 0, stream>>>(acc_b, den_b, bias_x, bias_h,
                                                ln_w, ln_b, hbuf, cbuf);
  }
  out_k<<<(NN + 3) / 4, 256, 0, stream>>>(hbuf, w1, b1, w2, b2, out);
}